// Round 1
// baseline (67.455 us; speedup 1.0000x reference)
//
#include <hip/hip_runtime.h>
#include <hip/hip_bf16.h>

#define THREADS 256
#define ROWS_PER_BLOCK 8
#define EMB_ROWS 5050

// Main kernel: each block handles ROWS_PER_BLOCK rows (i), each thread strides
// over columns (j). All pair work is fp32 VALU; emb table lives in LDS.
__global__ __launch_bounds__(THREADS, 2) void energy_main_kernel(
    const float* __restrict__ coords,
    const int*   __restrict__ atom_ix,
    const float* __restrict__ charges,
    const float* __restrict__ emb,
    const float* __restrict__ W1,
    const float* __restrict__ b1,
    const float* __restrict__ W2,
    const float* __restrict__ b2,
    float* __restrict__ partials,
    int n_atoms)
{
    __shared__ float s_emb[EMB_ROWS];
    for (int t = threadIdx.x; t < EMB_ROWS; t += THREADS) s_emb[t] = emb[t];

    // MLP weights: wave-uniform loads -> scalar regs / hoisted VGPRs.
    float A[16], Bw[16], Cb[16], U0[16], U1[16], U2[16];
#pragma unroll
    for (int k = 0; k < 16; ++k) {
        A[k]  = W1[k];        // W1[0][k]
        Bw[k] = W1[16 + k];   // W1[1][k]
        Cb[k] = b1[k];
        U0[k] = W2[3 * k + 0];
        U1[k] = W2[3 * k + 1];
        U2[k] = W2[3 * k + 2];
    }
    const float bo0 = b2[0], bo1 = b2[1], bo2 = b2[2];

    const int row0 = blockIdx.x * ROWS_PER_BLOCK;
    float xr[ROWS_PER_BLOCK], yr[ROWS_PER_BLOCK], zr[ROWS_PER_BLOCK], qr[ROWS_PER_BLOCK];
    int   br[ROWS_PER_BLOCK];
#pragma unroll
    for (int r = 0; r < ROWS_PER_BLOCK; ++r) {
        const int i = row0 + r;
        xr[r] = coords[3 * i + 0];
        yr[r] = coords[3 * i + 1];
        zr[r] = coords[3 * i + 2];
        qr[r] = charges[i];
        const int a = atom_ix[i];
        br[r] = (a * (a + 1)) >> 1;
    }
    __syncthreads();

    float cacc = 0.0f, ljacc = 0.0f;

#pragma unroll 1
    for (int j = threadIdx.x; j < n_atoms; j += THREADS) {
        const float xj = coords[3 * j + 0];
        const float yj = coords[3 * j + 1];
        const float zj = coords[3 * j + 2];
        const float qj = charges[j];
        const int   aj = atom_ix[j];

#pragma unroll
        for (int r = 0; r < ROWS_PER_BLOCK; ++r) {
            const float dx = xj - xr[r];
            const float dy = yj - yr[r];
            const float dz = zj - zr[r];
            const float sq = fmaf(dx, dx, fmaf(dy, dy, dz * dz));
            // sq==0 (diagonal): rsqrtf(0)=+inf, fminf(inf,10)=10 -> matches
            // reference's nan_to_num + clamp-to-10 semantics exactly.
            const float rd = fminf(rsqrtf(sq), 10.0f);

            const float e = s_emb[br[r] + aj];
            const float c = qr[r] * qj;

            float o0 = bo0, o1 = bo1, o2 = bo2;
#pragma unroll
            for (int k = 0; k < 16; ++k) {
                float h = fmaf(e, A[k], fmaf(c, Bw[k], Cb[k]));
                h = fmaxf(h, 0.0f);
                o0 = fmaf(h, U0[k], o0);
                o1 = fmaf(h, U1[k], o1);
                o2 = fmaf(h, U2[k], o2);
            }

            cacc = fmaf(o0, rd, cacc);
            const float sr  = o1 * rd;
            const float sr2 = sr * sr;
            const float sr6 = sr2 * sr2 * sr2;
            ljacc = fmaf(o2, fmaf(sr6, sr6, -sr6), ljacc);
        }
    }

    // Deterministic in-block reduction: wave shuffle, then LDS across waves.
#pragma unroll
    for (int off = 32; off > 0; off >>= 1) {
        cacc  += __shfl_down(cacc, off, 64);
        ljacc += __shfl_down(ljacc, off, 64);
    }
    __shared__ float s_c[THREADS / 64], s_l[THREADS / 64];
    const int wave = threadIdx.x >> 6;
    const int lane = threadIdx.x & 63;
    if (lane == 0) { s_c[wave] = cacc; s_l[wave] = ljacc; }
    __syncthreads();
    if (threadIdx.x == 0) {
        float ct = 0.0f, lt = 0.0f;
#pragma unroll
        for (int w = 0; w < THREADS / 64; ++w) { ct += s_c[w]; lt += s_l[w]; }
        partials[2 * blockIdx.x + 0] = ct;
        partials[2 * blockIdx.x + 1] = lt;
    }
}

// Final reduction over block partials (fixed order -> deterministic).
__global__ __launch_bounds__(THREADS, 1) void energy_reduce_kernel(
    const float* __restrict__ partials, int nblocks,
    const float* __restrict__ bias, float* __restrict__ out)
{
    float ct = 0.0f, lt = 0.0f;
    for (int b = threadIdx.x; b < nblocks; b += THREADS) {
        ct += partials[2 * b + 0];
        lt += partials[2 * b + 1];
    }
#pragma unroll
    for (int off = 32; off > 0; off >>= 1) {
        ct += __shfl_down(ct, off, 64);
        lt += __shfl_down(lt, off, 64);
    }
    __shared__ float s_c[THREADS / 64], s_l[THREADS / 64];
    const int wave = threadIdx.x >> 6;
    const int lane = threadIdx.x & 63;
    if (lane == 0) { s_c[wave] = ct; s_l[wave] = lt; }
    __syncthreads();
    if (threadIdx.x == 0) {
        float c = 0.0f, l = 0.0f;
#pragma unroll
        for (int w = 0; w < THREADS / 64; ++w) { c += s_c[w]; l += s_l[w]; }
        // COULOMB_CONSTANT = -1, EV = 1.602e-19
        out[0] = -c + 1.602e-19f * l + bias[0];
    }
}

extern "C" void kernel_launch(void* const* d_in, const int* in_sizes, int n_in,
                              void* d_out, int out_size, void* d_ws, size_t ws_size,
                              hipStream_t stream)
{
    const float* coords  = (const float*)d_in[0];
    const int*   atom_ix = (const int*)d_in[1];
    const float* charges = (const float*)d_in[2];
    const float* emb     = (const float*)d_in[3];
    const float* W1      = (const float*)d_in[4];
    const float* b1      = (const float*)d_in[5];
    const float* W2      = (const float*)d_in[6];
    const float* b2      = (const float*)d_in[7];
    const float* bias    = (const float*)d_in[8];

    float* out      = (float*)d_out;
    float* partials = (float*)d_ws;

    const int n       = in_sizes[1];              // 4096 atoms
    const int nblocks = n / ROWS_PER_BLOCK;       // 512 blocks

    energy_main_kernel<<<nblocks, THREADS, 0, stream>>>(
        coords, atom_ix, charges, emb, W1, b1, W2, b2, partials, n);
    energy_reduce_kernel<<<1, THREADS, 0, stream>>>(partials, nblocks, bias, out);
}